// Round 4
// baseline (182.117 us; speedup 1.0000x reference)
//
#include <hip/hip_runtime.h>
#include <hip/hip_bf16.h>
#include <math.h>

// Sizes (fixed by the reference problem)
#define BSZ 64
#define DV  1024
#define NQ  32
#define NS  1024
#define DD  128

#define ALPHA 0.5f
#define TS   64             // s-rows per multi block
#define NSR  (NS / TS)      // 16 s-slices
#define ROWB 272            // LDS row stride bytes: 256B data + 16B pad

typedef __attribute__((ext_vector_type(8))) short short8;   // 8 bf16 (4 VGPR) MFMA A/B frag
typedef __attribute__((ext_vector_type(4))) float floatx4;  // MFMA C/D frag

__device__ __forceinline__ unsigned short bf16_of(float x) {
    __hip_bfloat16 h = __float2bfloat16(x);
    return *(unsigned short*)&h;
}

// ---------------- prep: q_multi fp32->bf16 (blocks 0..63) + single-vector CE (blocks 64..127) ----
__global__ void prep_kernel(const float* __restrict__ qm,
                            const float* __restrict__ qs, const float* __restrict__ ds,
                            unsigned short* __restrict__ qb, float* __restrict__ svrow) {
    __shared__ float row[BSZ];
    if (blockIdx.x < 64) {
        int idx = blockIdx.x * 256 + threadIdx.x;
#pragma unroll
        for (int it = 0; it < 4; ++it) {
            int g = idx + it * 16384;             // 65536 float4 groups total
            float4 v = ((const float4*)qm)[g];
            ushort4 u;
            u.x = bf16_of(v.x); u.y = bf16_of(v.y); u.z = bf16_of(v.z); u.w = bf16_of(v.w);
            *(ushort4*)(qb + g * 4) = u;
        }
    } else {
        int b = blockIdx.x - 64;             // 0..63
        int t = threadIdx.x;                 // 256
        int c = t >> 2, part = t & 3;
        const float4* qv = (const float4*)(qs + b * DV);
        const float4* dv = (const float4*)(ds + c * DV);
        float acc = 0.f;
        int k0 = part * 64;
#pragma unroll 8
        for (int k = k0; k < k0 + 64; ++k) {
            float4 a = qv[k], bb = dv[k];
            acc += a.x * bb.x + a.y * bb.y + a.z * bb.z + a.w * bb.w;
        }
        acc += __shfl_xor(acc, 1);
        acc += __shfl_xor(acc, 2);
        if (part == 0) row[c] = acc;
        __syncthreads();
        if (t < BSZ) {
            float v = row[t];
            float m = v;
#pragma unroll
            for (int o = 1; o < 64; o <<= 1) m = fmaxf(m, __shfl_xor(m, o));
            float e = expf(v - m);
#pragma unroll
            for (int o = 1; o < 64; o <<= 1) e += __shfl_xor(e, o);
            float lse = m + logf(e);
            if (t == 0) svrow[b] = lse - row[b];
        }
    }
}

// ---------------- multi: block=(c,sr) computes chunk s-maxes for ALL 64 b ------
// A-operand = d-chunk (resident 64 VGPR), B-operand = q (streamed from L2).
// acc layout: col = n (lane&15), row = s (quad*4+reg) -> max over s is in-lane + 2 shuffles.
// partial[sr][c][b][n] = max over this chunk's 64 s of Q[b,n,:].D[c,s,:]
__launch_bounds__(256, 3)
__global__ void multi_kernel(const unsigned short* __restrict__ qb,
                             const float* __restrict__ dm,
                             float* __restrict__ partial) {
    int c  = blockIdx.x;         // 0..63
    int sr = blockIdx.y;         // 0..15
    int t  = threadIdx.x;        // 256
    int w  = t >> 6;             // wave 0..3 (owns b-range [w*16, w*16+16))
    int l  = t & 63;
    int lane16 = l & 15;
    int quad   = (l >> 4) & 3;

    __shared__ __align__(16) unsigned char dch[TS * ROWB];   // 17408 B bf16 chunk

    // ---- stage d[c, sr*64 .. +64) fp32 -> bf16 LDS, coalesced ----
    {
        const float4* src = (const float4*)(dm + ((size_t)c * NS + sr * TS) * DD);
#pragma unroll
        for (int p = 0; p < 8; ++p) {
            int f = p * 256 + t;                    // float4 group 0..2047 (32 per s-row)
            float4 v = src[f];
            ushort4 u;
            u.x = bf16_of(v.x); u.y = bf16_of(v.y); u.z = bf16_of(v.z); u.w = bf16_of(v.w);
            *(ushort4*)(dch + (f >> 5) * ROWB + (f & 31) * 8) = u;
        }
    }
    __syncthreads();

    // ---- A fragments (d-chunk), resident: A[m = s = lane&15][k = quad*8+j] ----
    short8 bf[4][4];
#pragma unroll
    for (int st = 0; st < 4; ++st)
#pragma unroll
        for (int ks = 0; ks < 4; ++ks)
            bf[st][ks] = *(const short8*)(dch + (st * 16 + lane16) * ROWB + ks * 64 + quad * 16);

    float* pout = partial + (size_t)(sr * BSZ + c) * BSZ * NQ;

    // B fragments (q), double-buffered: B[n = lane&15][k = quad*8+j], [nt*4+ks]
    short8 bqA[8], bqB[8];
    auto loadq = [&](short8* dst, int b) {
        const unsigned short* p2 = qb + ((size_t)b * NQ + lane16) * DD + quad * 8;
#pragma unroll
        for (int nt = 0; nt < 2; ++nt)
#pragma unroll
            for (int ks = 0; ks < 4; ++ks)
                dst[nt * 4 + ks] = *(const short8*)(p2 + nt * 16 * DD + ks * 32);
    };

    int b0 = w * 16;
    loadq(bqA, b0);
#pragma unroll
    for (int i = 0; i < 16; ++i) {
        const short8* cur = (i & 1) ? bqB : bqA;
        short8* nxt       = (i & 1) ? bqA : bqB;
        if (i < 15) loadq(nxt, b0 + i + 1);

        float mx0 = -1e30f, mx1 = -1e30f;
#pragma unroll
        for (int st = 0; st < 4; ++st) {
            floatx4 a0 = (floatx4){0.f, 0.f, 0.f, 0.f};
            floatx4 a1 = (floatx4){0.f, 0.f, 0.f, 0.f};
#pragma unroll
            for (int ks = 0; ks < 4; ++ks) {
                a0 = __builtin_amdgcn_mfma_f32_16x16x32_bf16(bf[st][ks], cur[ks],     a0, 0, 0, 0);
                a1 = __builtin_amdgcn_mfma_f32_16x16x32_bf16(bf[st][ks], cur[4 + ks], a1, 0, 0, 0);
            }
#pragma unroll
            for (int r = 0; r < 4; ++r) {
                mx0 = fmaxf(mx0, a0[r]);
                mx1 = fmaxf(mx1, a1[r]);
            }
        }
        // max across quads (rows s = quad*4+r): lanes differing in bits 4,5
        mx0 = fmaxf(mx0, __shfl_xor(mx0, 16));
        mx0 = fmaxf(mx0, __shfl_xor(mx0, 32));
        mx1 = fmaxf(mx1, __shfl_xor(mx1, 16));
        mx1 = fmaxf(mx1, __shfl_xor(mx1, 32));

        int b = b0 + i;
        if (quad == 0)      pout[(size_t)b * NQ + lane16]      = mx0;
        else if (quad == 1) pout[(size_t)b * NQ + 16 + lane16] = mx1;
    }
}

// ---------------- reduce: scores[b][c] = sum_n max_sr partial[sr][c][b][n] ----------------
__global__ void reduce_kernel(const float* __restrict__ partial, float* __restrict__ scores) {
    int p = blockIdx.x * 256 + threadIdx.x;   // 0..4095
    int c = p >> 6, b = p & 63;
    float4 mx[8];
#pragma unroll
    for (int j = 0; j < 8; ++j) mx[j] = make_float4(-1e30f, -1e30f, -1e30f, -1e30f);
    for (int sr = 0; sr < NSR; ++sr) {
        const float4* q = (const float4*)(partial + ((size_t)(sr * BSZ + c) * BSZ + b) * NQ);
#pragma unroll
        for (int j = 0; j < 8; ++j) {
            float4 v = q[j];
            mx[j].x = fmaxf(mx[j].x, v.x); mx[j].y = fmaxf(mx[j].y, v.y);
            mx[j].z = fmaxf(mx[j].z, v.z); mx[j].w = fmaxf(mx[j].w, v.w);
        }
    }
    float s = 0.f;
#pragma unroll
    for (int j = 0; j < 8; ++j) s += mx[j].x + mx[j].y + mx[j].z + mx[j].w;
    scores[b * BSZ + c] = s;
}

// ---------------- finisher: combine both losses ----------------
__global__ void finish_kernel(const float* __restrict__ scores, const float* __restrict__ svrow,
                              float* __restrict__ out) {
    int t = threadIdx.x;  // 64
    float pos = scores[t * BSZ + t];
    float neg = -1e30f;
    for (int cc = 0; cc < BSZ; ++cc)
        if (cc != t) neg = fmaxf(neg, scores[t * BSZ + cc]);
    float x = neg - pos;
    float sp = fmaxf(x, 0.f) + log1pf(expf(-fabsf(x)));   // stable softplus
    float sv = svrow[t];
#pragma unroll
    for (int o = 1; o < 64; o <<= 1) {
        sp += __shfl_xor(sp, o);
        sv += __shfl_xor(sv, o);
    }
    if (t == 0) out[0] = ALPHA * sv + (1.0f - ALPHA) * (sp * (1.0f / BSZ));
}

// ---------------- launch ----------------
extern "C" void kernel_launch(void* const* d_in, const int* in_sizes, int n_in,
                              void* d_out, int out_size, void* d_ws, size_t ws_size,
                              hipStream_t stream) {
    const float* q_single = (const float*)d_in[0];
    const float* d_single = (const float*)d_in[1];
    const float* q_multi  = (const float*)d_in[2];
    const float* d_multi  = (const float*)d_in[3];
    float* out = (float*)d_out;

    // ws: qb 512KB | partial 8MB | scores 16KB | svrow 256B
    unsigned short* qb = (unsigned short*)d_ws;
    float* partial     = (float*)((char*)d_ws + 524288);
    float* scores      = (float*)((char*)d_ws + 524288 + 8388608);
    float* svrow       = (float*)((char*)d_ws + 524288 + 8388608 + 16384);

    prep_kernel<<<128, 256, 0, stream>>>(q_multi, q_single, d_single, qb, svrow);
    multi_kernel<<<dim3(BSZ, NSR), 256, 0, stream>>>(qb, d_multi, partial);
    reduce_kernel<<<16, 256, 0, stream>>>(partial, scores);
    finish_kernel<<<1, 64, 0, stream>>>(scores, svrow, out);
}

// Round 5
// 138.295 us; speedup vs baseline: 1.3169x; 1.3169x over previous
//
#include <hip/hip_runtime.h>
#include <hip/hip_bf16.h>
#include <math.h>

// Sizes (fixed by the reference problem)
#define BSZ 64
#define DV  1024
#define NQ  32
#define NS  1024
#define DD  128

#define ALPHA 0.5f

typedef __attribute__((ext_vector_type(8))) short short8;   // 8 bf16 (4 VGPR) MFMA A/B frag
typedef __attribute__((ext_vector_type(4))) float floatx4;  // MFMA C/D frag

__device__ __forceinline__ unsigned short bf16_of(float x) {
    __hip_bfloat16 h = __float2bfloat16(x);
    return *(unsigned short*)&h;
}

// ==================== prep ====================
// blocks 0..1023   : d_multi fp32 -> bf16, swizzled to MFMA B-frag chunk order
//                    chunk g=(c,st,ks,l): lane l holds d[c][st*16+(l&15)][ks*32+((l>>4)&3)*8 .. +8]
// blocks 1024..1055: q_multi fp32 -> bf16, swizzled to MFMA A-frag chunk order
//                    chunk h=(b,nt,ks,l): lane l holds q[b][nt*16+(l&15)][ks*32+((l>>4)&3)*8 .. +8]
// blocks 1056..1119: single-vector CE loss rows
__global__ void prep_kernel(const float* __restrict__ qm, const float* __restrict__ dm,
                            const float* __restrict__ qs, const float* __restrict__ ds,
                            unsigned short* __restrict__ qbs, unsigned short* __restrict__ dbs,
                            float* __restrict__ svrow) {
    __shared__ float row[BSZ];
    int bid = blockIdx.x, t = threadIdx.x;
    if (bid < 1024) {
#pragma unroll
        for (int it = 0; it < 4; ++it) {
            int g = it * 262144 + bid * 256 + t;       // 1,048,576 chunks of 16B
            int l = g & 63, ks = (g >> 6) & 3, st = (g >> 8) & 63, c = g >> 14;
            int srcrow = st * 16 + (l & 15);
            int kb = ks * 32 + ((l >> 4) & 3) * 8;
            const float* p = dm + ((size_t)(c * NS + srcrow)) * DD + kb;
            float4 v0 = *(const float4*)p;
            float4 v1 = *(const float4*)(p + 4);
            short8 o;
            o[0] = (short)bf16_of(v0.x); o[1] = (short)bf16_of(v0.y);
            o[2] = (short)bf16_of(v0.z); o[3] = (short)bf16_of(v0.w);
            o[4] = (short)bf16_of(v1.x); o[5] = (short)bf16_of(v1.y);
            o[6] = (short)bf16_of(v1.z); o[7] = (short)bf16_of(v1.w);
            *(short8*)(dbs + (size_t)g * 8) = o;
        }
    } else if (bid < 1056) {
#pragma unroll
        for (int it = 0; it < 4; ++it) {
            int h = it * 8192 + (bid - 1024) * 256 + t;  // 32768 chunks
            int l = h & 63, ks = (h >> 6) & 3, nt = (h >> 8) & 1, b = h >> 9;
            int srcrow = b * NQ + nt * 16 + (l & 15);
            int kb = ks * 32 + ((l >> 4) & 3) * 8;
            const float* p = qm + (size_t)srcrow * DD + kb;
            float4 v0 = *(const float4*)p;
            float4 v1 = *(const float4*)(p + 4);
            short8 o;
            o[0] = (short)bf16_of(v0.x); o[1] = (short)bf16_of(v0.y);
            o[2] = (short)bf16_of(v0.z); o[3] = (short)bf16_of(v0.w);
            o[4] = (short)bf16_of(v1.x); o[5] = (short)bf16_of(v1.y);
            o[6] = (short)bf16_of(v1.z); o[7] = (short)bf16_of(v1.w);
            *(short8*)(qbs + (size_t)h * 8) = o;
        }
    } else {
        int b = bid - 1056;                  // 0..63
        int c = t >> 2, part = t & 3;
        const float4* qv = (const float4*)(qs + b * DV);
        const float4* dv = (const float4*)(ds + c * DV);
        float acc = 0.f;
        int k0 = part * 64;
#pragma unroll 8
        for (int k = k0; k < k0 + 64; ++k) {
            float4 a = qv[k], bb = dv[k];
            acc += a.x * bb.x + a.y * bb.y + a.z * bb.z + a.w * bb.w;
        }
        acc += __shfl_xor(acc, 1);
        acc += __shfl_xor(acc, 2);
        if (part == 0) row[c] = acc;
        __syncthreads();
        if (t < BSZ) {
            float v = row[t];
            float m = v;
#pragma unroll
            for (int o = 1; o < 64; o <<= 1) m = fmaxf(m, __shfl_xor(m, o));
            float e = expf(v - m);
#pragma unroll
            for (int o = 1; o < 64; o <<= 1) e += __shfl_xor(e, o);
            float lse = m + logf(e);
            if (t == 0) svrow[b] = lse - row[b];
        }
    }
}

// ==================== multi ====================
// block = (bg of 4 b's, c); waves split the 64 s-tiles (wave w gets tiles w+4i).
// LDS-free main loop: coalesced dwordx4 B-loads from pre-swizzled dbs (L2-resident
// per XCD via bid&7 -> c-octet decode), register double-buffer, running max in regs.
// Single cross-lane/cross-wave reduction at the end; writes scores directly.
__launch_bounds__(256, 2)
__global__ void multi_kernel(const unsigned short* __restrict__ qbs,
                             const unsigned short* __restrict__ dbs,
                             float* __restrict__ scores) {
    int bid = blockIdx.x;            // 0..1023
    int x = bid & 7, rr = bid >> 3;
    int c  = x * 8 + (rr & 7);       // XCD x keeps c in [8x, 8x+8): 2MB of dbs -> L2-resident
    int bg = rr >> 3;                // 0..15
    int t  = threadIdx.x;
    int w  = t >> 6;
    int l  = t & 63;
    int lane16 = l & 15;
    int quad   = (l >> 4) & 3;

    __shared__ float smax[4][4][NQ];

    // A-frags (q), loaded once, fully coalesced from swizzled qbs
    short8 af[4][2][4];
#pragma unroll
    for (int bi = 0; bi < 4; ++bi)
#pragma unroll
        for (int nt = 0; nt < 2; ++nt)
#pragma unroll
            for (int ks = 0; ks < 4; ++ks)
                af[bi][nt][ks] = *(const short8*)(qbs +
                    ((size_t)((((bg * 4 + bi) * 2 + nt) * 4 + ks) * 64 + l)) * 8);

    float mx[4][2][4];
#pragma unroll
    for (int bi = 0; bi < 4; ++bi)
#pragma unroll
        for (int nt = 0; nt < 2; ++nt)
#pragma unroll
            for (int r = 0; r < 4; ++r) mx[bi][nt][r] = -1e30f;

    // B-tile load: chunk (c, st, ks) -> 1KB contiguous, lane l at +l*16B
    short8 bf[2][4];
    auto loadb = [&](short8* dst, int st) {
        const unsigned short* p = dbs + ((size_t)((c * 64 + st) * 4) * 64 + l) * 8;
#pragma unroll
        for (int ks = 0; ks < 4; ++ks)
            dst[ks] = *(const short8*)(p + (size_t)ks * 512);
    };

    loadb(bf[0], w);
#pragma unroll
    for (int i = 0; i < 16; ++i) {
        if (i < 15) loadb(bf[(i + 1) & 1], w + (i + 1) * 4);
        const short8* B = bf[i & 1];
        floatx4 acc[4][2];
#pragma unroll
        for (int bi = 0; bi < 4; ++bi)
#pragma unroll
            for (int nt = 0; nt < 2; ++nt) acc[bi][nt] = (floatx4){0.f, 0.f, 0.f, 0.f};
#pragma unroll
        for (int ks = 0; ks < 4; ++ks)
#pragma unroll
            for (int bi = 0; bi < 4; ++bi)
#pragma unroll
                for (int nt = 0; nt < 2; ++nt)
                    acc[bi][nt] = __builtin_amdgcn_mfma_f32_16x16x32_bf16(
                        af[bi][nt][ks], B[ks], acc[bi][nt], 0, 0, 0);
        // C/D layout: col(s)=lane&15, row(n)=quad*4+reg -> independent running fmax only
#pragma unroll
        for (int bi = 0; bi < 4; ++bi)
#pragma unroll
            for (int nt = 0; nt < 2; ++nt)
#pragma unroll
                for (int r = 0; r < 4; ++r)
                    mx[bi][nt][r] = fmaxf(mx[bi][nt][r], acc[bi][nt][r]);
    }

    // ---- single end-of-kernel reduction (round-1 verified path) ----
#pragma unroll
    for (int bi = 0; bi < 4; ++bi)
#pragma unroll
        for (int nt = 0; nt < 2; ++nt)
#pragma unroll
            for (int r = 0; r < 4; ++r) {
                float v = mx[bi][nt][r];
                v = fmaxf(v, __shfl_xor(v, 1));
                v = fmaxf(v, __shfl_xor(v, 2));
                v = fmaxf(v, __shfl_xor(v, 4));
                v = fmaxf(v, __shfl_xor(v, 8));
                mx[bi][nt][r] = v;
            }
    if (lane16 == 0) {
#pragma unroll
        for (int bi = 0; bi < 4; ++bi)
#pragma unroll
            for (int nt = 0; nt < 2; ++nt)
#pragma unroll
                for (int r = 0; r < 4; ++r)
                    smax[w][bi][nt * 16 + quad * 4 + r] = mx[bi][nt][r];
    }
    __syncthreads();
    if (t < 4 * NQ) {
        int bi = t >> 5, n = t & 31;
        float v = fmaxf(fmaxf(smax[0][bi][n], smax[1][bi][n]),
                        fmaxf(smax[2][bi][n], smax[3][bi][n]));
#pragma unroll
        for (int o = 1; o < 32; o <<= 1) v += __shfl_xor(v, o);
        if (n == 0) scores[(bg * 4 + bi) * BSZ + c] = v;
    }
}

// ==================== finisher ====================
__global__ void finish_kernel(const float* __restrict__ scores, const float* __restrict__ svrow,
                              float* __restrict__ out) {
    int t = threadIdx.x;  // 64
    float pos = scores[t * BSZ + t];
    float neg = -1e30f;
    for (int cc = 0; cc < BSZ; ++cc)
        if (cc != t) neg = fmaxf(neg, scores[t * BSZ + cc]);
    float xx = neg - pos;
    float sp = fmaxf(xx, 0.f) + log1pf(expf(-fabsf(xx)));   // stable softplus
    float sv = svrow[t];
#pragma unroll
    for (int o = 1; o < 64; o <<= 1) {
        sp += __shfl_xor(sp, o);
        sv += __shfl_xor(sv, o);
    }
    if (t == 0) out[0] = ALPHA * sv + (1.0f - ALPHA) * (sp * (1.0f / BSZ));
}

// ==================== launch ====================
extern "C" void kernel_launch(void* const* d_in, const int* in_sizes, int n_in,
                              void* d_out, int out_size, void* d_ws, size_t ws_size,
                              hipStream_t stream) {
    const float* q_single = (const float*)d_in[0];
    const float* d_single = (const float*)d_in[1];
    const float* q_multi  = (const float*)d_in[2];
    const float* d_multi  = (const float*)d_in[3];
    float* out = (float*)d_out;

    // ws: qbs 512KB | dbs 16MB | scores 16KB | svrow 256B
    unsigned short* qbs = (unsigned short*)d_ws;
    unsigned short* dbs = (unsigned short*)((char*)d_ws + 524288);
    float* scores       = (float*)((char*)d_ws + 524288 + 16777216);
    float* svrow        = (float*)((char*)d_ws + 524288 + 16777216 + 16384);

    prep_kernel<<<1120, 256, 0, stream>>>(q_multi, d_multi, q_single, d_single,
                                          qbs, dbs, svrow);
    multi_kernel<<<1024, 256, 0, stream>>>(qbs, dbs, scores);
    finish_kernel<<<1, 64, 0, stream>>>(scores, svrow, out);
}

// Round 6
// 122.892 us; speedup vs baseline: 1.4819x; 1.1253x over previous
//
#include <hip/hip_runtime.h>
#include <hip/hip_bf16.h>
#include <math.h>

// Sizes (fixed by the reference problem)
#define BSZ 64
#define DV  1024
#define NQ  32
#define NS  1024
#define DD  128

#define ALPHA 0.5f

typedef __attribute__((ext_vector_type(8))) int   int8v;    // 32B fp8 MFMA A/B frag (8 VGPR)
typedef __attribute__((ext_vector_type(4))) float floatx4;  // MFMA C/D frag
#define SCALE1 127      // e8m0 byte 0x7F = 2^0 = 1.0

// ==================== prep ====================
// blocks 0..255  : d_multi fp32 -> fp8(e4m3), swizzled to 16x16x128 B-frag chunks
//                  chunk ch=(c,st): lane l holds d[c][st*16+(l&15)][((l>>4)&3)*32 .. +32] (32B)
// blocks 256..263: q_multi fp32 -> fp8, A-frag chunks: (b,nt): lane l holds
//                  q[b][nt*16+(l&15)][((l>>4)&3)*32 .. +32]
// blocks 264..327: single-vector CE loss rows (exact fp32)
__global__ void prep_kernel(const float* __restrict__ qm, const float* __restrict__ dm,
                            const float* __restrict__ qs, const float* __restrict__ ds,
                            unsigned char* __restrict__ qb8, unsigned char* __restrict__ db8,
                            float* __restrict__ svrow) {
    __shared__ float row[BSZ];
    int bid = blockIdx.x, t = threadIdx.x;
    int w = t >> 6, l = t & 63;
    int lane16 = l & 15, quad = (l >> 4) & 3;

    auto cvt_chunk = [&](const float* src, unsigned char* dst) {
        // src: 32 contiguous floats for this lane; dst: 32 bytes at lane slot
        int dw[8];
#pragma unroll
        for (int j = 0; j < 8; ++j) {
            float4 v = ((const float4*)src)[j];
            int d0 = __builtin_amdgcn_cvt_pk_fp8_f32(v.x, v.y, 0, false);
            dw[j]  = __builtin_amdgcn_cvt_pk_fp8_f32(v.z, v.w, d0, true);
        }
        ((int4*)dst)[0] = make_int4(dw[0], dw[1], dw[2], dw[3]);
        ((int4*)dst)[1] = make_int4(dw[4], dw[5], dw[6], dw[7]);
    };

    if (bid < 256) {
        int gw = bid * 4 + w;                 // 1024 waves
#pragma unroll
        for (int it = 0; it < 4; ++it) {
            int ch = gw + it * 1024;          // 4096 chunks (c*64+st)
            int c = ch >> 6, st = ch & 63;
            const float* src = dm + ((size_t)(c * NS + st * 16 + lane16)) * DD + quad * 32;
            cvt_chunk(src, db8 + (size_t)ch * 2048 + l * 32);
        }
    } else if (bid < 264) {
        int gw = (bid - 256) * 4 + w;         // 32 waves
#pragma unroll
        for (int it = 0; it < 4; ++it) {
            int ch = gw * 4 + it;             // 128 chunks (b*2+nt)
            int b = ch >> 1, nt = ch & 1;
            const float* src = qm + ((size_t)(b * NQ + nt * 16 + lane16)) * DD + quad * 32;
            cvt_chunk(src, qb8 + (size_t)ch * 2048 + l * 32);
        }
    } else {
        int b = bid - 264;                    // 0..63
        int c = t >> 2, part = t & 3;
        const float4* qv = (const float4*)(qs + b * DV);
        const float4* dv = (const float4*)(ds + c * DV);
        float acc = 0.f;
        int k0 = part * 64;
#pragma unroll 8
        for (int k = k0; k < k0 + 64; ++k) {
            float4 a = qv[k], bb = dv[k];
            acc += a.x * bb.x + a.y * bb.y + a.z * bb.z + a.w * bb.w;
        }
        acc += __shfl_xor(acc, 1);
        acc += __shfl_xor(acc, 2);
        if (part == 0) row[c] = acc;
        __syncthreads();
        if (t < BSZ) {
            float v = row[t];
            float m = v;
#pragma unroll
            for (int o = 1; o < 64; o <<= 1) m = fmaxf(m, __shfl_xor(m, o));
            float e = expf(v - m);
#pragma unroll
            for (int o = 1; o < 64; o <<= 1) e += __shfl_xor(e, o);
            float lse = m + logf(e);
            if (t == 0) svrow[b] = lse - row[b];
        }
    }
}

// ==================== multi (MX-fp8, K=128 in one MFMA) ====================
// block = (bg of 4 b's, c); wave w owns s-tiles st = w+4i. One mfma_scale per
// (bi,nt,st) computes the full 16x16 score tile over D=128. LDS-free main loop,
// register double-buffered B, running max in regs, single end reduction.
__launch_bounds__(256, 2)
__global__ void multi_kernel(const unsigned char* __restrict__ qb8,
                             const unsigned char* __restrict__ db8,
                             float* __restrict__ scores) {
    int bid = blockIdx.x;            // 0..1023
    int x = bid & 7, rr = bid >> 3;
    int c  = x * 8 + (rr & 7);       // XCD x keeps c in [8x,8x+8): 1MB of db8 -> L2-resident
    int bg = rr >> 3;                // 0..15
    int t  = threadIdx.x;
    int w  = t >> 6;
    int l  = t & 63;
    int lane16 = l & 15;
    int quad   = (l >> 4) & 3;

    __shared__ float smax[4][4][NQ];

    // A-frags (q), loaded once, coalesced (lane l at +l*32B within 2KB chunk)
    int8v af[4][2];
#pragma unroll
    for (int bi = 0; bi < 4; ++bi)
#pragma unroll
        for (int nt = 0; nt < 2; ++nt)
            af[bi][nt] = *(const int8v*)(qb8 +
                (size_t)(((bg * 4 + bi) * 2 + nt) * 2048) + l * 32);

    float mx[4][2][4];
#pragma unroll
    for (int bi = 0; bi < 4; ++bi)
#pragma unroll
        for (int nt = 0; nt < 2; ++nt)
#pragma unroll
            for (int r = 0; r < 4; ++r) mx[bi][nt][r] = -1e30f;

    int8v bf[2];
    auto loadb = [&](int which, int st) {
        bf[which] = *(const int8v*)(db8 + (size_t)((c * 64 + st) * 2048) + l * 32);
    };

    loadb(0, w);
#pragma unroll
    for (int i = 0; i < 16; ++i) {
        if (i < 15) loadb((i + 1) & 1, w + (i + 1) * 4);
        int8v B = bf[i & 1];
#pragma unroll
        for (int bi = 0; bi < 4; ++bi)
#pragma unroll
            for (int nt = 0; nt < 2; ++nt) {
                floatx4 acc = __builtin_amdgcn_mfma_scale_f32_16x16x128_f8f6f4(
                    af[bi][nt], B, (floatx4){0.f, 0.f, 0.f, 0.f},
                    0, 0,                 // cbsz=fp8(e4m3), blgp=fp8(e4m3)
                    0, SCALE1,            // scale_a: opsel 0, byte 0x7F = 1.0
                    0, SCALE1);           // scale_b
                // C/D: col(s)=lane&15, row(n)=quad*4+r -> independent running fmax
#pragma unroll
                for (int r = 0; r < 4; ++r)
                    mx[bi][nt][r] = fmaxf(mx[bi][nt][r], acc[r]);
            }
    }

    // ---- single end-of-kernel reduction (round-1/5 verified path) ----
#pragma unroll
    for (int bi = 0; bi < 4; ++bi)
#pragma unroll
        for (int nt = 0; nt < 2; ++nt)
#pragma unroll
            for (int r = 0; r < 4; ++r) {
                float v = mx[bi][nt][r];
                v = fmaxf(v, __shfl_xor(v, 1));
                v = fmaxf(v, __shfl_xor(v, 2));
                v = fmaxf(v, __shfl_xor(v, 4));
                v = fmaxf(v, __shfl_xor(v, 8));
                mx[bi][nt][r] = v;
            }
    if (lane16 == 0) {
#pragma unroll
        for (int bi = 0; bi < 4; ++bi)
#pragma unroll
            for (int nt = 0; nt < 2; ++nt)
#pragma unroll
                for (int r = 0; r < 4; ++r)
                    smax[w][bi][nt * 16 + quad * 4 + r] = mx[bi][nt][r];
    }
    __syncthreads();
    if (t < 4 * NQ) {
        int bi = t >> 5, n = t & 31;
        float v = fmaxf(fmaxf(smax[0][bi][n], smax[1][bi][n]),
                        fmaxf(smax[2][bi][n], smax[3][bi][n]));
#pragma unroll
        for (int o = 1; o < 32; o <<= 1) v += __shfl_xor(v, o);
        if (n == 0) scores[(bg * 4 + bi) * BSZ + c] = v;
    }
}

// ==================== finisher ====================
__global__ void finish_kernel(const float* __restrict__ scores, const float* __restrict__ svrow,
                              float* __restrict__ out) {
    int t = threadIdx.x;  // 64
    float pos = scores[t * BSZ + t];
    float neg = -1e30f;
    for (int cc = 0; cc < BSZ; ++cc)
        if (cc != t) neg = fmaxf(neg, scores[t * BSZ + cc]);
    float xx = neg - pos;
    float sp = fmaxf(xx, 0.f) + log1pf(expf(-fabsf(xx)));   // stable softplus
    float sv = svrow[t];
#pragma unroll
    for (int o = 1; o < 64; o <<= 1) {
        sp += __shfl_xor(sp, o);
        sv += __shfl_xor(sv, o);
    }
    if (t == 0) out[0] = ALPHA * sv + (1.0f - ALPHA) * (sp * (1.0f / BSZ));
}

// ==================== launch ====================
extern "C" void kernel_launch(void* const* d_in, const int* in_sizes, int n_in,
                              void* d_out, int out_size, void* d_ws, size_t ws_size,
                              hipStream_t stream) {
    const float* q_single = (const float*)d_in[0];
    const float* d_single = (const float*)d_in[1];
    const float* q_multi  = (const float*)d_in[2];
    const float* d_multi  = (const float*)d_in[3];
    float* out = (float*)d_out;

    // ws: qb8 256KB | db8 8MB | scores 16KB | svrow 256B
    unsigned char* qb8 = (unsigned char*)d_ws;
    unsigned char* db8 = (unsigned char*)d_ws + 262144;
    float* scores      = (float*)((char*)d_ws + 262144 + 8388608);
    float* svrow       = (float*)((char*)d_ws + 262144 + 8388608 + 16384);

    prep_kernel<<<328, 256, 0, stream>>>(q_multi, d_multi, q_single, d_single,
                                         qb8, db8, svrow);
    multi_kernel<<<1024, 256, 0, stream>>>(qb8, db8, scores);
    finish_kernel<<<1, 64, 0, stream>>>(scores, svrow, out);
}